// Round 1
// baseline (140.644 us; speedup 1.0000x reference)
//
#include <hip/hip_runtime.h>

// HistogramLoss: total = emd(hist(rgb_in),hist(rgb_ref)) + emd(hist(yuv_in),hist(yuv_ref))
// emd collapses to sum_k (64-k)*(h1_k - h2_k); hist bins tile [-0.05,1.05] disjointly,
// so per pixel-channel exactly one bin (candidate +-1 checked for f32-center rounding).
// All boundary math in f64 with f32-rounded constants to match the np float64 reference.

#define HW    65536      // 256*256
#define BATCH 8
#define NPIX  (BATCH * HW)   // 524288 pixel positions
#define BLOCK 256
#define NBLK  (NPIX / BLOCK) // 2048

__global__ void hl_init(double* ws) {
  if (threadIdx.x == 0) {
    ws[0] = 0.0;            // integer-part accumulator (exact)
    ws[1] = 0.0;            // epsilon-part accumulator
    ((int*)(ws + 2))[0] = 0; // finished-block counter
  }
}

__device__ __forceinline__ void channel_contrib(double v, double sign,
    const float* __restrict__ centers, double width, double L, double step,
    double& aW, double& aE) {
  // v in raw [-1,1]-ish domain; reference scales: u = (v+1)*0.5
  double u = (v + 1.0) * 0.5;
  double q = (u + 0.05) / step;     // bin guess in f64
  int kf = (int)floor(q);
  #pragma unroll
  for (int dk = -1; dk <= 1; ++dk) {
    int k = kf + dk;
    if ((unsigned)k < 64u) {
      double d = fabs(u - (double)centers[k]);
      double t = width - d;         // act = 1.01f^t ; act > 1  <=>  t > 0  (f64 semantics)
      if (t > 0.0) {
        double z = L * t;           // z <= 8.6e-5: 3-term expm1 is ~1e-9 relative
        double e = z * (1.0 + z * (0.5 + z * (1.0 / 6.0)));
        double w = (double)(64 - k);
        aW += sign * w;             // exact integer part
        aE += sign * (w * e);       // tiny soft part
      }
    }
  }
}

__global__ __launch_bounds__(BLOCK) void hl_main(
    const float* __restrict__ img_in, const float* __restrict__ img_ref,
    float* __restrict__ out, double* __restrict__ ws) {
  __shared__ float centers[64];
  __shared__ double red[8];

  // Replicate np.linspace(-0.05, 1.05, 65) in f64, then the f32 casts the module does.
  const double start = -0.05;
  const double span  = 1.05 - (-0.05);       // fl(1.1)
  const double step  = span / 64.0;          // exact /2^6
  const double e1    = 1.0 * step + start;   // edges[1] = fl(fl(1*step)+start)
  const double e2    = 2.0 * step + start;   // edges[2]
  const double halfw = (e2 - e1) * 0.5;      // delta/2 in f64
  const float  widthf = (float)halfw;        // _WIDTH = float32(delta/2)
  if (threadIdx.x < 64) {
    double edge = (double)(int)threadIdx.x * step + start;
    centers[threadIdx.x] = (float)(edge + halfw);  // _CENTERS float32
  }
  __syncthreads();

  const double width = (double)widthf;
  const double L = log((double)1.01f);       // base is float32(1.01) promoted to f64

  double aW = 0.0, aE = 0.0;
  {
    int p  = blockIdx.x * BLOCK + threadIdx.x;  // grid covers NPIX exactly
    int b  = p >> 16;
    int hw = p & (HW - 1);
    const float* pi = img_in  + (size_t)b * (3 * HW) + hw;
    const float* pr = img_ref + (size_t)b * (3 * HW) + hw;
    double r0 = (double)pi[0], g0 = (double)pi[HW], b0 = (double)pi[2 * HW];
    double r1 = (double)pr[0], g1 = (double)pr[HW], b1 = (double)pr[2 * HW];

    // RGB space
    channel_contrib(r0,  1.0, centers, width, L, step, aW, aE);
    channel_contrib(g0,  1.0, centers, width, L, step, aW, aE);
    channel_contrib(b0,  1.0, centers, width, L, step, aW, aE);
    channel_contrib(r1, -1.0, centers, width, L, step, aW, aE);
    channel_contrib(g1, -1.0, centers, width, L, step, aW, aE);
    channel_contrib(b1, -1.0, centers, width, L, step, aW, aE);

    // YUV space — f32-rounded coefficients, f64 dot (matches np promotion)
    const double Y0 = (double)0.299f,    Y1 = (double)0.587f,    Y2 = (double)0.114f;
    const double U0 = (double)-0.14713f, U1 = (double)-0.28886f, U2 = (double)0.436f;
    const double V0 = (double)0.615f,    V1 = (double)-0.51499f, V2 = (double)-0.10001f;

    double yi = Y0 * r0 + Y1 * g0 + Y2 * b0;
    double ui = U0 * r0 + U1 * g0 + U2 * b0;
    double vi = V0 * r0 + V1 * g0 + V2 * b0;
    double yr = Y0 * r1 + Y1 * g1 + Y2 * b1;
    double ur = U0 * r1 + U1 * g1 + U2 * b1;
    double vr = V0 * r1 + V1 * g1 + V2 * b1;

    channel_contrib(yi,  1.0, centers, width, L, step, aW, aE);
    channel_contrib(ui,  1.0, centers, width, L, step, aW, aE);
    channel_contrib(vi,  1.0, centers, width, L, step, aW, aE);
    channel_contrib(yr, -1.0, centers, width, L, step, aW, aE);
    channel_contrib(ur, -1.0, centers, width, L, step, aW, aE);
    channel_contrib(vr, -1.0, centers, width, L, step, aW, aE);
  }

  // wave(64) shuffle reduction, then cross-wave via LDS
  #pragma unroll
  for (int off = 32; off > 0; off >>= 1) {
    aW += __shfl_down(aW, off);
    aE += __shfl_down(aE, off);
  }
  int wave = threadIdx.x >> 6;
  if ((threadIdx.x & 63) == 0) { red[wave * 2] = aW; red[wave * 2 + 1] = aE; }
  __syncthreads();

  if (threadIdx.x == 0) {
    double sW = 0.0, sE = 0.0;
    #pragma unroll
    for (int w = 0; w < 4; ++w) { sW += red[w * 2]; sE += red[w * 2 + 1]; }
    atomicAdd(&ws[0], sW);
    atomicAdd(&ws[1], sE);
    __threadfence();
    int done = atomicAdd((int*)(ws + 2), 1);
    if (done == NBLK - 1) {
      __threadfence();
      double tW = atomicAdd(&ws[0], 0.0);   // coherent device-scope reads
      double tE = atomicAdd(&ws[1], 0.0);
      out[0] = (float)((tW + tE) * (1.0 / (double)NPIX));
    }
  }
}

extern "C" void kernel_launch(void* const* d_in, const int* in_sizes, int n_in,
                              void* d_out, int out_size, void* d_ws, size_t ws_size,
                              hipStream_t stream) {
  const float* img_in  = (const float*)d_in[0];
  const float* img_ref = (const float*)d_in[1];
  float* out = (float*)d_out;
  double* ws = (double*)d_ws;

  hl_init<<<1, 64, 0, stream>>>(ws);
  hl_main<<<NBLK, BLOCK, 0, stream>>>(img_in, img_ref, out, ws);
}

// Round 2
// 72.248 us; speedup vs baseline: 1.9467x; 1.9467x over previous
//
#include <hip/hip_runtime.h>

// HistogramLoss: total = emd(hist(rgb_in),hist(rgb_ref)) + emd(hist(yuv_in),hist(yuv_ref))
// emd collapses to sum_k (64-k)*(h1_k - h2_k); bins tile [-0.05,1.05] disjointly,
// so per pixel-channel exactly one bin (candidate +-1 checked for f32-center rounding).
// Boundary math in f64 with f32-rounded constants to match the np float64 reference.
//
// R2: atomic-free reduction. R1 spent ~75 us serializing 6144 same-address
// device atomics (VALUBusy 10%, HBM 1%, avg occupancy 24%). Now: kernel 1
// writes per-block partials (no init needed — unconditional stores), kernel 2
// (1 block) reduces them.

#define HW    65536      // 256*256
#define BATCH 8
#define NPIX  (BATCH * HW)   // 524288 pixel positions
#define BLOCK 256
#define NBLK  (NPIX / BLOCK) // 2048

__device__ __forceinline__ void channel_contrib(double v, double sign,
    const float* __restrict__ centers, double width, double L, double inv_step,
    double& aW, double& aE) {
  // v in raw [-1,1]-ish domain; reference scales: u = (v+1)*0.5
  double u = (v + 1.0) * 0.5;
  double q = (u + 0.05) * inv_step;  // bin guess (mul, not div — guess only, +-1 scanned)
  int kf = (int)floor(q);
  #pragma unroll
  for (int dk = -1; dk <= 1; ++dk) {
    int k = kf + dk;
    if ((unsigned)k < 64u) {
      double d = fabs(u - (double)centers[k]);
      double t = width - d;          // act = 1.01f^t ; act > 1  <=>  t > 0  (f64 semantics)
      if (t > 0.0) {
        double z = L * t;            // z <= 8.6e-5: 3-term expm1 is ~1e-14 relative
        double e = z * (1.0 + z * (0.5 + z * (1.0 / 6.0)));
        double w = (double)(64 - k);
        aW += sign * w;              // exact integer part
        aE += sign * (w * e);        // tiny soft part
      }
    }
  }
}

__global__ __launch_bounds__(BLOCK) void hl_partial(
    const float* __restrict__ img_in, const float* __restrict__ img_ref,
    double* __restrict__ partials) {
  __shared__ float centers[64];
  __shared__ double red[8];

  // Replicate np.linspace(-0.05, 1.05, 65) in f64, then the module's f32 casts.
  const double start = -0.05;
  const double span  = 1.05 - (-0.05);       // fl(1.1)
  const double step  = span / 64.0;          // exact /2^6
  const double e1    = 1.0 * step + start;
  const double e2    = 2.0 * step + start;
  const double halfw = (e2 - e1) * 0.5;      // delta/2 in f64
  const float  widthf = (float)halfw;        // _WIDTH = float32(delta/2)
  if (threadIdx.x < 64) {
    double edge = (double)(int)threadIdx.x * step + start;
    centers[threadIdx.x] = (float)(edge + halfw);  // _CENTERS float32
  }
  __syncthreads();

  const double width = (double)widthf;
  const double L = log((double)1.01f);       // base = float32(1.01) promoted to f64
  const double inv_step = 1.0 / step;

  double aW = 0.0, aE = 0.0;
  {
    int p  = blockIdx.x * BLOCK + threadIdx.x;  // grid covers NPIX exactly
    int b  = p >> 16;
    int hw = p & (HW - 1);
    const float* pi = img_in  + (size_t)b * (3 * HW) + hw;
    const float* pr = img_ref + (size_t)b * (3 * HW) + hw;
    double r0 = (double)pi[0], g0 = (double)pi[HW], b0 = (double)pi[2 * HW];
    double r1 = (double)pr[0], g1 = (double)pr[HW], b1 = (double)pr[2 * HW];

    // RGB space
    channel_contrib(r0,  1.0, centers, width, L, inv_step, aW, aE);
    channel_contrib(g0,  1.0, centers, width, L, inv_step, aW, aE);
    channel_contrib(b0,  1.0, centers, width, L, inv_step, aW, aE);
    channel_contrib(r1, -1.0, centers, width, L, inv_step, aW, aE);
    channel_contrib(g1, -1.0, centers, width, L, inv_step, aW, aE);
    channel_contrib(b1, -1.0, centers, width, L, inv_step, aW, aE);

    // YUV space — f32-rounded coefficients, f64 dot (matches np promotion)
    const double Y0 = (double)0.299f,    Y1 = (double)0.587f,    Y2 = (double)0.114f;
    const double U0 = (double)-0.14713f, U1 = (double)-0.28886f, U2 = (double)0.436f;
    const double V0 = (double)0.615f,    V1 = (double)-0.51499f, V2 = (double)-0.10001f;

    double yi = Y0 * r0 + Y1 * g0 + Y2 * b0;
    double ui = U0 * r0 + U1 * g0 + U2 * b0;
    double vi = V0 * r0 + V1 * g0 + V2 * b0;
    double yr = Y0 * r1 + Y1 * g1 + Y2 * b1;
    double ur = U0 * r1 + U1 * g1 + U2 * b1;
    double vr = V0 * r1 + V1 * g1 + V2 * b1;

    channel_contrib(yi,  1.0, centers, width, L, inv_step, aW, aE);
    channel_contrib(ui,  1.0, centers, width, L, inv_step, aW, aE);
    channel_contrib(vi,  1.0, centers, width, L, inv_step, aW, aE);
    channel_contrib(yr, -1.0, centers, width, L, inv_step, aW, aE);
    channel_contrib(ur, -1.0, centers, width, L, inv_step, aW, aE);
    channel_contrib(vr, -1.0, centers, width, L, inv_step, aW, aE);
  }

  // wave(64) shuffle reduction, then cross-wave via LDS
  #pragma unroll
  for (int off = 32; off > 0; off >>= 1) {
    aW += __shfl_down(aW, off);
    aE += __shfl_down(aE, off);
  }
  int wave = threadIdx.x >> 6;
  if ((threadIdx.x & 63) == 0) { red[wave * 2] = aW; red[wave * 2 + 1] = aE; }
  __syncthreads();

  if (threadIdx.x == 0) {
    double sW = 0.0, sE = 0.0;
    #pragma unroll
    for (int w = 0; w < 4; ++w) { sW += red[w * 2]; sE += red[w * 2 + 1]; }
    partials[2 * blockIdx.x]     = sW;  // unconditional store: no ws init required
    partials[2 * blockIdx.x + 1] = sE;
  }
}

__global__ __launch_bounds__(BLOCK) void hl_final(
    const double* __restrict__ partials, float* __restrict__ out) {
  __shared__ double red[8];
  double sW = 0.0, sE = 0.0;
  for (int b = threadIdx.x; b < NBLK; b += BLOCK) {
    sW += partials[2 * b];
    sE += partials[2 * b + 1];
  }
  #pragma unroll
  for (int off = 32; off > 0; off >>= 1) {
    sW += __shfl_down(sW, off);
    sE += __shfl_down(sE, off);
  }
  int wave = threadIdx.x >> 6;
  if ((threadIdx.x & 63) == 0) { red[wave * 2] = sW; red[wave * 2 + 1] = sE; }
  __syncthreads();
  if (threadIdx.x == 0) {
    double tW = 0.0, tE = 0.0;
    #pragma unroll
    for (int w = 0; w < 4; ++w) { tW += red[w * 2]; tE += red[w * 2 + 1]; }
    out[0] = (float)((tW + tE) * (1.0 / (double)NPIX));
  }
}

extern "C" void kernel_launch(void* const* d_in, const int* in_sizes, int n_in,
                              void* d_out, int out_size, void* d_ws, size_t ws_size,
                              hipStream_t stream) {
  const float* img_in  = (const float*)d_in[0];
  const float* img_ref = (const float*)d_in[1];
  float* out = (float*)d_out;
  double* partials = (double*)d_ws;   // 2*NBLK doubles = 32 KB

  hl_partial<<<NBLK, BLOCK, 0, stream>>>(img_in, img_ref, partials);
  hl_final<<<1, BLOCK, 0, stream>>>(partials, out);
}

// Round 3
// 69.611 us; speedup vs baseline: 2.0204x; 1.0379x over previous
//
#include <hip/hip_runtime.h>

// HistogramLoss: total = emd(hist(rgb_in),hist(rgb_ref)) + emd(hist(yuv_in),hist(yuv_ref))
// emd collapses to sum_k (64-k)*(h1_k - h2_k); bins tile [-0.05,1.05] disjointly.
// R3: f64 kept ONLY for (a) the in-window decision t = width-|u-c_k| > 0 and
// (b) the YUV dot (both must match the np float64 reference bit-for-bit-ish);
// bin guess is one f32 fma (2 candidates suffice: guess error ~1e-5 bins vs
// 0.5-bin margin), integer weight accumulates in int32 (exact), soft part
// expm1(L*t) ~ z+z^2/2 in f32 from the f64 t (error ~1e-9/term).
// R2 counters: top-5 dispatches are all 41us harness d_ws poison fills —
// harness floor ~45-50us; this round targets hl_partial's f64-VALU time.

#define HW    65536             // 256*256
#define NPIX  524288            // 8 * HW pixel positions
#define BLOCK 256
#define PXT   2                 // pixels per thread
#define NBLK  (NPIX / (BLOCK * PXT))   // 1024

__device__ __forceinline__ void contrib(double v, float vf,
    const float* __restrict__ centers, double width, float ga, float gb, float Lf,
    int& aW, float& aE) {
  // guess: g = ((v+1)*0.5 + 0.05)/step - 0.5  ==  v*ga + gb ; candidates k0, k0+1
  float gg = fmaf(vf, ga, gb);
  int k0 = (int)floorf(gg);
  double u = (v + 1.0) * 0.5;           // exact f64 op, matches np
  #pragma unroll
  for (int dk = 0; dk <= 1; ++dk) {
    int k = k0 + dk;
    if ((unsigned)k < 64u) {
      double d = u - (double)centers[k];   // f64: decision must match np
      double t = width - fabs(d);
      if (t > 0.0) {                       // act = 1.01^t > 1  <=>  t > 0
        float tf = (float)t;               // t <= 8.6e-3: f32 fine for soft part
        float z  = Lf * tf;                // z <= 8.6e-5
        float e  = fmaf(0.5f * z, z, z);   // expm1(z), O(z^3) dropped (~1e-13)
        int   w  = 64 - k;
        aW += w;                           // exact integer part
        aE  = fmaf((float)w, e, aE);       // tiny soft part
      }
    }
  }
}

__global__ __launch_bounds__(BLOCK) void hl_partial(
    const float* __restrict__ img_in, const float* __restrict__ img_ref,
    double* __restrict__ partials) {
  __shared__ float centers[64];
  __shared__ double redW[4], redE[4];

  // Replicate np.linspace(-0.05, 1.05, 65) in f64, then the module's f32 casts.
  const double start = -0.05;
  const double step  = (1.05 - (-0.05)) / 64.0;  // fl(1.1) / 2^6 (exact div)
  const double e1    = 1.0 * step + start;
  const double e2    = 2.0 * step + start;
  const double halfw = (e2 - e1) * 0.5;          // delta/2 in f64
  const float  widthf = (float)halfw;            // _WIDTH = float32(delta/2)
  if (threadIdx.x < 64) {
    double edge = (double)(int)threadIdx.x * step + start;
    centers[threadIdx.x] = (float)(edge + halfw);  // _CENTERS float32
  }
  __syncthreads();

  const double width = (double)widthf;
  const float  Lf = (float)log((double)1.01f);   // ln(float32(1.01))
  const float  ga = (float)(0.5 / step);         // guess-only constants (f32 ok)
  const float  gb = (float)(0.55 / step - 0.5);

  // f32-rounded YUV coefficients, f64 dot (matches np promotion; j-order = np einsum)
  const double Y0 = (double)0.299f,    Y1 = (double)0.587f,    Y2 = (double)0.114f;
  const double U0 = (double)-0.14713f, U1 = (double)-0.28886f, U2 = (double)0.436f;
  const double V0 = (double)0.615f,    V1 = (double)-0.51499f, V2 = (double)-0.10001f;

  int   aWp = 0,  aWn = 0;      // + image / - image integer parts (exact)
  float aEp = 0.f, aEn = 0.f;   // soft parts

  const int base = blockIdx.x * (BLOCK * PXT) + threadIdx.x;
  #pragma unroll
  for (int i = 0; i < PXT; ++i) {
    int p  = base + i * BLOCK;           // coalesced
    int b  = p >> 16;
    int hw = p & (HW - 1);
    const float* pi = img_in  + (size_t)b * (3 * HW) + hw;
    const float* pr = img_ref + (size_t)b * (3 * HW) + hw;
    float r0 = pi[0], g0 = pi[HW], b0 = pi[2 * HW];
    float r1 = pr[0], g1 = pr[HW], b1 = pr[2 * HW];

    // RGB
    contrib((double)r0, r0, centers, width, ga, gb, Lf, aWp, aEp);
    contrib((double)g0, g0, centers, width, ga, gb, Lf, aWp, aEp);
    contrib((double)b0, b0, centers, width, ga, gb, Lf, aWp, aEp);
    contrib((double)r1, r1, centers, width, ga, gb, Lf, aWn, aEn);
    contrib((double)g1, g1, centers, width, ga, gb, Lf, aWn, aEn);
    contrib((double)b1, b1, centers, width, ga, gb, Lf, aWn, aEn);

    // YUV (f64 values feed the decision; f32 shadow feeds the guess)
    double yi = fma(Y2, (double)b0, fma(Y1, (double)g0, Y0 * (double)r0));
    double ui = fma(U2, (double)b0, fma(U1, (double)g0, U0 * (double)r0));
    double vi = fma(V2, (double)b0, fma(V1, (double)g0, V0 * (double)r0));
    double yr = fma(Y2, (double)b1, fma(Y1, (double)g1, Y0 * (double)r1));
    double ur = fma(U2, (double)b1, fma(U1, (double)g1, U0 * (double)r1));
    double vr = fma(V2, (double)b1, fma(V1, (double)g1, V0 * (double)r1));

    contrib(yi, (float)yi, centers, width, ga, gb, Lf, aWp, aEp);
    contrib(ui, (float)ui, centers, width, ga, gb, Lf, aWp, aEp);
    contrib(vi, (float)vi, centers, width, ga, gb, Lf, aWp, aEp);
    contrib(yr, (float)yr, centers, width, ga, gb, Lf, aWn, aEn);
    contrib(ur, (float)ur, centers, width, ga, gb, Lf, aWn, aEn);
    contrib(vr, (float)vr, centers, width, ga, gb, Lf, aWn, aEn);
  }

  int    aW = aWp - aWn;                      // exact int diff
  double aE = (double)aEp - (double)aEn;

  // wave(64) shuffle reduction, then cross-wave via LDS
  #pragma unroll
  for (int off = 32; off > 0; off >>= 1) {
    aW += __shfl_down(aW, off);
    aE += __shfl_down(aE, off);
  }
  int wv = threadIdx.x >> 6;
  if ((threadIdx.x & 63) == 0) { redW[wv] = (double)aW; redE[wv] = aE; }
  __syncthreads();

  if (threadIdx.x == 0) {
    double sW = 0.0, sE = 0.0;
    #pragma unroll
    for (int w = 0; w < 4; ++w) { sW += redW[w]; sE += redE[w]; }
    partials[2 * blockIdx.x]     = sW;  // unconditional store: no ws init needed
    partials[2 * blockIdx.x + 1] = sE;
  }
}

__global__ __launch_bounds__(BLOCK) void hl_final(
    const double* __restrict__ partials, float* __restrict__ out) {
  __shared__ double redW[4], redE[4];
  double sW = 0.0, sE = 0.0;
  for (int b = threadIdx.x; b < NBLK; b += BLOCK) {
    sW += partials[2 * b];
    sE += partials[2 * b + 1];
  }
  #pragma unroll
  for (int off = 32; off > 0; off >>= 1) {
    sW += __shfl_down(sW, off);
    sE += __shfl_down(sE, off);
  }
  int wv = threadIdx.x >> 6;
  if ((threadIdx.x & 63) == 0) { redW[wv] = sW; redE[wv] = sE; }
  __syncthreads();
  if (threadIdx.x == 0) {
    double tW = 0.0, tE = 0.0;
    #pragma unroll
    for (int w = 0; w < 4; ++w) { tW += redW[w]; tE += redE[w]; }
    out[0] = (float)((tW + tE) * (1.0 / (double)NPIX));
  }
}

extern "C" void kernel_launch(void* const* d_in, const int* in_sizes, int n_in,
                              void* d_out, int out_size, void* d_ws, size_t ws_size,
                              hipStream_t stream) {
  const float* img_in  = (const float*)d_in[0];
  const float* img_ref = (const float*)d_in[1];
  float* out = (float*)d_out;
  double* partials = (double*)d_ws;   // 2*NBLK doubles = 16 KB

  hl_partial<<<NBLK, BLOCK, 0, stream>>>(img_in, img_ref, partials);
  hl_final<<<1, BLOCK, 0, stream>>>(partials, out);
}